// Round 12
// baseline (142.526 us; speedup 1.0000x reference)
//
#include <hip/hip_runtime.h>
#include <hip/hip_bf16.h>

// GCNConv: out = scatter_add_row( norm[e] * (x@W)[col[e]] ) + bias
// Round 12: A/B split — standalone LDS-free MFMA GEMM + standalone build
// kernel (R11's two-pass LDS counting-sort). Tests whether the R8 merge's
// shared 26.9KB static LDS was throttling GEMM-block occupancy.

#define NBLK_B  512     // build blocks
#define BSHIFT  8       // 256 nodes per bucket
#define NPB     256
#define REC_CAP 3456    // max edges per build block chunk
#define CAPMAX  5632    // max records per bucket

typedef __attribute__((ext_vector_type(8))) short bf16x8;
typedef __attribute__((ext_vector_type(4))) float f32x4;

__device__ __forceinline__ uint32_t f2bf_rne(float f) {
    uint32_t u = __float_as_uint(f);
    return (u + 0x7fffu + ((u >> 16) & 1u)) >> 16;
}
__device__ __forceinline__ float bf_lo(uint32_t u) { return __uint_as_float(u << 16); }
__device__ __forceinline__ float bf_hi(uint32_t u) { return __uint_as_float(u & 0xffff0000u); }

__device__ __forceinline__ bf16x8 pack8(float4 lo, float4 hi) {
    union { bf16x8 v; ushort u[8]; } r;
    r.u[0] = (ushort)f2bf_rne(lo.x);
    r.u[1] = (ushort)f2bf_rne(lo.y);
    r.u[2] = (ushort)f2bf_rne(lo.z);
    r.u[3] = (ushort)f2bf_rne(lo.w);
    r.u[4] = (ushort)f2bf_rne(hi.x);
    r.u[5] = (ushort)f2bf_rne(hi.y);
    r.u[6] = (ushort)f2bf_rne(hi.z);
    r.u[7] = (ushort)f2bf_rne(hi.w);
    return r.v;
}

// ---------------- W -> Wt bf16 transposed; also zero bucket cursors ---------
__global__ void wconv_kernel(const float* __restrict__ W, ushort* __restrict__ Wt,
                             int* __restrict__ gcur, int nbuck) {
    int t = blockIdx.x * blockDim.x + threadIdx.x;   // 0..16383
    int n = t >> 7, k = t & 127;
    Wt[n * 128 + k] = (ushort)f2bf_rne(W[k * 128 + n]);
    if (t < nbuck) gcur[t] = 0;
}

// ---------------- standalone MFMA GEMM (no LDS) ----------------
__global__ __launch_bounds__(256) void mfma_gemm(const float* __restrict__ X,
                                                 const ushort* __restrict__ Wt,
                                                 uint32_t* __restrict__ S, int N) {
    const int wave = threadIdx.x >> 6;
    const int lane = threadIdx.x & 63;
    const int c16  = lane & 15;
    const int kg   = lane >> 4;
    const int row0 = blockIdx.x * 128 + wave * 32;

    int rA0 = row0 + c16;
    int rA1 = row0 + 16 + c16;
    if (rA0 >= N) rA0 = N - 1;
    if (rA1 >= N) rA1 = N - 1;

    f32x4 acc[2][8];
#pragma unroll
    for (int m = 0; m < 2; ++m)
#pragma unroll
        for (int cb = 0; cb < 8; ++cb) acc[m][cb] = (f32x4){0.f, 0.f, 0.f, 0.f};

    const float*  xa0 = X + (size_t)rA0 * 128 + kg * 8;
    const float*  xa1 = X + (size_t)rA1 * 128 + kg * 8;
    const ushort* wb  = Wt + kg * 8 + c16 * 128;

#pragma unroll
    for (int kk = 0; kk < 4; ++kk) {
        float4 a0lo = *(const float4*)(xa0 + kk * 32);
        float4 a0hi = *(const float4*)(xa0 + kk * 32 + 4);
        float4 a1lo = *(const float4*)(xa1 + kk * 32);
        float4 a1hi = *(const float4*)(xa1 + kk * 32 + 4);
        bf16x8 A0 = pack8(a0lo, a0hi);
        bf16x8 A1 = pack8(a1lo, a1hi);
#pragma unroll
        for (int cb = 0; cb < 8; ++cb) {
            bf16x8 B = *(const bf16x8*)(wb + (size_t)cb * 16 * 128 + kk * 32);
            acc[0][cb] = __builtin_amdgcn_mfma_f32_16x16x32_bf16(A0, B, acc[0][cb], 0, 0, 0);
            acc[1][cb] = __builtin_amdgcn_mfma_f32_16x16x32_bf16(A1, B, acc[1][cb], 0, 0, 0);
        }
    }
#pragma unroll
    for (int m = 0; m < 2; ++m) {
#pragma unroll
        for (int i = 0; i < 4; ++i) {
            int gr = row0 + m * 16 + kg * 4 + i;
            if (gr < N) {
#pragma unroll
                for (int cb = 0; cb < 4; ++cb) {
                    uint32_t p = f2bf_rne(acc[m][cb][i]) |
                                 (f2bf_rne(acc[m][cb + 4][i]) << 16);
                    S[(size_t)gr * 64 + cb * 16 + c16] = p;
                }
            }
        }
    }
}

// ---------------- standalone build: LDS counting-sort, coalesced part -------
__global__ __launch_bounds__(256) void build_kernel(
        const int* __restrict__ row, const int* __restrict__ col,
        uint32_t* __restrict__ part, int* __restrict__ gcur,
        int E, int chunk, int nbuck, int cap) {
    __shared__ __align__(16) char smem[26880];
    uint32_t* rec  = (uint32_t*)smem;                 // [REC_CAP]
    ushort*   rbk  = (ushort*)(smem + 13824);         // [REC_CAP]
    int*      hist = (int*)(smem + 20736);            // [512]
    int*      lst  = (int*)(smem + 22784);            // [512]
    int*      resv = (int*)(smem + 24832);            // [512]
    const int blk = blockIdx.x;
    const int t = threadIdx.x;
    int lo = blk * chunk, hi = min(E, lo + chunk);
    int cnt = hi - lo;

    for (int i = t; i < 512; i += 256) hist[i] = 0;
    __syncthreads();
    for (int i = t; i < cnt; i += 256)
        atomicAdd(&hist[row[lo + i] >> BSHIFT], 1);
    __syncthreads();
    int a0 = hist[2 * t], a1 = hist[2 * t + 1];
    int v2 = a0 + a1;
    resv[t] = v2;
    __syncthreads();
#pragma unroll
    for (int o = 1; o < 256; o <<= 1) {
        int u = (t >= o) ? resv[t - o] : 0;
        __syncthreads();
        resv[t] += u;
        __syncthreads();
    }
    int ex = resv[t] - v2;
    lst[2 * t]     = ex;
    lst[2 * t + 1] = ex + a0;
    __syncthreads();
    for (int b = t; b < nbuck; b += 256) {
        int c = hist[b];
        resv[b] = (c > 0) ? atomicAdd(&gcur[b], c) : 0;
    }
    __syncthreads();
    for (int i = t; i < 512; i += 256) hist[i] = lst[i];
    __syncthreads();
    for (int i = t; i < cnt; i += 256) {
        int r = row[lo + i], c = col[lo + i];
        int b = r >> BSHIFT;
        int p = atomicAdd(&hist[b], 1);
        rec[p] = ((uint32_t)(r & (NPB - 1)) << 17) | (uint32_t)c;
        rbk[p] = (ushort)b;
    }
    __syncthreads();
    for (int i = t; i < cnt; i += 256) {
        int b = rbk[i];
        int off = resv[b] + (i - lst[b]);
        if (off < cap)
            part[(size_t)b * cap + off] = rec[i];
    }
}

// ---------------- P3: per-bucket CSR via LDS image, coalesced out -----------
__global__ __launch_bounds__(1024) void p3_build(const uint32_t* __restrict__ part,
                                                 const int* __restrict__ gcur,
                                                 int* __restrict__ rowstart,
                                                 int* __restrict__ rowend,
                                                 float* __restrict__ dis,
                                                 int* __restrict__ csr,
                                                 int N, int nbuck, int cap) {
    __shared__ uint32_t recl[CAPMAX];
    __shared__ int csrl[CAPMAX];
    __shared__ int hist[NPB];
    __shared__ int lst[NPB];
    __shared__ int s[NPB];
    const int b = blockIdx.x, t = threadIdx.x;
    const int base = b * cap;
    int cb = gcur[b];
    if (cb > cap) cb = cap;

    if (t < NPB) hist[t] = 0;
    __syncthreads();
    for (int i = t; i < cb; i += 1024) {
        uint32_t p = part[base + i];
        recl[i] = p;
        atomicAdd(&hist[p >> 17], 1);
    }
    __syncthreads();

    int v = 0;
    if (t < NPB) { v = hist[t]; s[t] = v; }
    __syncthreads();
#pragma unroll
    for (int o = 1; o < NPB; o <<= 1) {
        int u = 0;
        if (t < NPB && t >= o) u = s[t - o];
        __syncthreads();
        if (t < NPB && t >= o) s[t] += u;
        __syncthreads();
    }
    if (t < NPB) {
        int ex = s[t] - v;
        lst[t] = ex;
        int node = (b << BSHIFT) + t;
        if (node < N) {
            rowstart[node] = base + ex;
            rowend[node]   = base + ex + v;
            dis[node]      = rsqrtf((float)v);
        }
        hist[t] = ex;    // cursor
    }
    __syncthreads();
    for (int i = t; i < cb; i += 1024) {
        uint32_t p = recl[i];
        int q = atomicAdd(&hist[p >> 17], 1);
        csrl[q] = (int)(p & 0x1FFFFu);
    }
    __syncthreads();
    for (int i = t; i < cb; i += 1024)
        csr[base + i] = csrl[i];
}

// ---------------- wide gather: 4 edges per VMEM instr (at roofline) ---------
__global__ __launch_bounds__(256) void gather_kernel(const int* __restrict__ csr,
                                                     const int* __restrict__ rowstart,
                                                     const int* __restrict__ rowend,
                                                     const float* __restrict__ dis,
                                                     const uint4* __restrict__ sup,
                                                     const float* __restrict__ bias,
                                                     float* __restrict__ out, int N) {
    int wid  = (blockIdx.x * blockDim.x + threadIdx.x) >> 6;
    int lane = threadIdx.x & 63;
    if (wid >= N) return;
    const int grp = lane >> 4;
    const int li  = lane & 15;
    int begin = rowstart[wid];
    int end   = rowend[wid];
    int endm1 = end - 1;
    float dr  = dis[wid];

    float4 aL = make_float4(0.f, 0.f, 0.f, 0.f);
    float4 aH = make_float4(0.f, 0.f, 0.f, 0.f);

    for (int j = begin; j < end; j += 8) {
        int e0 = j + grp, e1 = j + 4 + grp;
        int c0 = csr[min(e0, endm1)];
        int c1 = csr[min(e1, endm1)];
        float n0 = (e0 < end) ? dr * dis[c0] : 0.f;
        float n1 = (e1 < end) ? dr * dis[c1] : 0.f;
        uint4 u0 = sup[(size_t)c0 * 16 + li];
        uint4 u1 = sup[(size_t)c1 * 16 + li];
        aL.x += n0 * bf_lo(u0.x) + n1 * bf_lo(u1.x);
        aL.y += n0 * bf_lo(u0.y) + n1 * bf_lo(u1.y);
        aL.z += n0 * bf_lo(u0.z) + n1 * bf_lo(u1.z);
        aL.w += n0 * bf_lo(u0.w) + n1 * bf_lo(u1.w);
        aH.x += n0 * bf_hi(u0.x) + n1 * bf_hi(u1.x);
        aH.y += n0 * bf_hi(u0.y) + n1 * bf_hi(u1.y);
        aH.z += n0 * bf_hi(u0.z) + n1 * bf_hi(u1.z);
        aH.w += n0 * bf_hi(u0.w) + n1 * bf_hi(u1.w);
    }

#pragma unroll
    for (int off = 16; off < 64; off <<= 1) {
        aL.x += __shfl_xor(aL.x, off);
        aL.y += __shfl_xor(aL.y, off);
        aL.z += __shfl_xor(aL.z, off);
        aL.w += __shfl_xor(aL.w, off);
        aH.x += __shfl_xor(aH.x, off);
        aH.y += __shfl_xor(aH.y, off);
        aH.z += __shfl_xor(aH.z, off);
        aH.w += __shfl_xor(aH.w, off);
    }

    if (grp == 0) {
        float4 bL = *(const float4*)(bias + li * 4);
        float4 bH = *(const float4*)(bias + 64 + li * 4);
        aL.x += bL.x; aL.y += bL.y; aL.z += bL.z; aL.w += bL.w;
        aH.x += bH.x; aH.y += bH.y; aH.z += bH.z; aH.w += bH.w;
        *(float4*)(out + (size_t)wid * 128 + li * 4)      = aL;
        *(float4*)(out + (size_t)wid * 128 + 64 + li * 4) = aH;
    }
}

// ---------------- fallback path (global-atomic CSR build, fp32 GEMM) --------
#define SCAN_B 256
__global__ void scan_block_kernel(const int* __restrict__ in, int* __restrict__ outp,
                                  int* __restrict__ bsum, int M) {
    __shared__ int s[SCAN_B];
    int t = threadIdx.x;
    int g = blockIdx.x * SCAN_B + t;
    int v = (g < M) ? in[g] : 0;
    s[t] = v;
    __syncthreads();
#pragma unroll
    for (int off = 1; off < SCAN_B; off <<= 1) {
        int u = (t >= off) ? s[t - off] : 0;
        __syncthreads();
        s[t] += u;
        __syncthreads();
    }
    if (g < M) outp[g] = s[t] - v;
    if (t == SCAN_B - 1) bsum[blockIdx.x] = s[t];
}
__global__ void scan_bsum_kernel(int* __restrict__ bsum, int NB) {
    __shared__ int s[1024];
    int t = threadIdx.x;
    int v = (t < NB) ? bsum[t] : 0;
    s[t] = v;
    __syncthreads();
#pragma unroll
    for (int off = 1; off < 1024; off <<= 1) {
        int u = (t >= off) ? s[t - off] : 0;
        __syncthreads();
        s[t] += u;
        __syncthreads();
    }
    if (t < NB) bsum[t] = s[t] - v;
}
__global__ void scan_add_kernel(int* __restrict__ outp, const int* __restrict__ bsum, int M) {
    int g = blockIdx.x * blockDim.x + threadIdx.x;
    if (g < M) outp[g] += bsum[g >> 8];
}
#define GB_M 64
#define GB_KC 32
__global__ __launch_bounds__(256) void gemm_kernel(const float* __restrict__ X,
                                                   const float* __restrict__ W,
                                                   uint32_t* __restrict__ S, int N) {
    __shared__ float sXT[GB_KC][72];
    __shared__ float sW[GB_KC][128];
    const int t  = threadIdx.x;
    const int tx = t & 15;
    const int ty = t >> 4;
    const int bm = blockIdx.x * GB_M;

    float acc[4][8];
#pragma unroll
    for (int i = 0; i < 4; ++i)
#pragma unroll
        for (int j = 0; j < 8; ++j) acc[i][j] = 0.f;

    const int sr = t >> 2;
    const int sc = (t & 3) << 2;

    for (int k0 = 0; k0 < 128; k0 += GB_KC) {
#pragma unroll
        for (int h = 0; h < 2; ++h) {
            int kk = sc + h * 16;
            int gr = bm + sr;
            float4 v = make_float4(0.f, 0.f, 0.f, 0.f);
            if (gr < N) v = *(const float4*)(X + (size_t)gr * 128 + k0 + kk);
            sXT[kk + 0][sr] = v.x;
            sXT[kk + 1][sr] = v.y;
            sXT[kk + 2][sr] = v.z;
            sXT[kk + 3][sr] = v.w;
        }
#pragma unroll
        for (int h = 0; h < 4; ++h) {
            int idx = t + h * 256;
            int wk  = idx >> 5;
            int wo  = (idx & 31) << 2;
            *(float4*)&sW[wk][wo] = *(const float4*)(W + (size_t)(k0 + wk) * 128 + wo);
        }
        __syncthreads();
#pragma unroll
        for (int k = 0; k < GB_KC; ++k) {
            float4 a  = *(const float4*)&sXT[k][ty * 4];
            float4 b0 = *(const float4*)&sW[k][tx * 4];
            float4 b1 = *(const float4*)&sW[k][64 + tx * 4];
            float av[4] = {a.x, a.y, a.z, a.w};
            float bv[8] = {b0.x, b0.y, b0.z, b0.w, b1.x, b1.y, b1.z, b1.w};
#pragma unroll
            for (int i = 0; i < 4; ++i)
#pragma unroll
                for (int j = 0; j < 8; ++j) acc[i][j] += av[i] * bv[j];
        }
        __syncthreads();
    }
#pragma unroll
    for (int i = 0; i < 4; ++i) {
        int gr = bm + ty * 4 + i;
        if (gr < N) {
            uint4 q;
            q.x = f2bf_rne(acc[i][0]) | (f2bf_rne(acc[i][4]) << 16);
            q.y = f2bf_rne(acc[i][1]) | (f2bf_rne(acc[i][5]) << 16);
            q.z = f2bf_rne(acc[i][2]) | (f2bf_rne(acc[i][6]) << 16);
            q.w = f2bf_rne(acc[i][3]) | (f2bf_rne(acc[i][7]) << 16);
            *(uint4*)(S + (size_t)gr * 64 + tx * 4) = q;
        }
    }
}
__global__ void deg_i_kernel(const int* __restrict__ row, int* __restrict__ degi, int E) {
    int g = blockIdx.x * blockDim.x + threadIdx.x;
    if (g < E) atomicAdd(&degi[row[g]], 1);
}
__global__ void rsqrt_i_kernel(const int* __restrict__ degi, float* __restrict__ dis, int N) {
    int g = blockIdx.x * blockDim.x + threadIdx.x;
    if (g < N) dis[g] = rsqrtf((float)degi[g]);
}
__global__ void fill_kernel(const int* __restrict__ row, const int* __restrict__ col,
                            int* __restrict__ start, int* __restrict__ csr, int E) {
    int e = blockIdx.x * blockDim.x + threadIdx.x;
    if (e < E) {
        int pos = atomicAdd(&start[row[e]], 1);
        csr[pos] = col[e];
    }
}
__global__ void rowptr_from_start_kernel(const int* __restrict__ startv,
                                         int* __restrict__ rowptr, int N, int E) {
    int g = blockIdx.x * blockDim.x + threadIdx.x;
    if (g < N) rowptr[g] = startv[g];
    if (g == 0) rowptr[N] = E;
}

extern "C" void kernel_launch(void* const* d_in, const int* in_sizes, int n_in,
                              void* d_out, int out_size, void* d_ws, size_t ws_size,
                              hipStream_t stream) {
    const float* x    = (const float*)d_in[0];
    const int*   ei   = (const int*)d_in[1];
    const float* W    = (const float*)d_in[2];
    const float* bias = (const float*)d_in[3];
    float*       out  = (float*)d_out;

    const int N = in_sizes[0] / 128;
    const int E = in_sizes[1] / 2;
    const int* row = ei;
    const int* col = ei + E;

    const int nbuck = (N + NPB - 1) >> BSHIFT;
    int cap = (E + nbuck - 1) / nbuck;
    cap += cap / 4 + 128;
    cap = (cap + 63) & ~63;
    const int chunkB = (E + NBLK_B - 1) / NBLK_B;
    const int GB = (N + 127) / 128;

    auto al = [](size_t v) { return (v + 511) & ~(size_t)511; };
    size_t o_gcur = 0;
    size_t o_rs   = al(o_gcur + (size_t)nbuck * 4);
    size_t o_re   = al(o_rs + (size_t)N * 4);
    size_t o_dis  = al(o_re + (size_t)N * 4);
    size_t o_csr  = al(o_dis + (size_t)N * 4);
    size_t o_part = al(o_csr + (size_t)nbuck * cap * 4);
    size_t o_wt   = al(o_part + (size_t)nbuck * cap * 4);
    size_t o_sup  = al(o_wt + 128 * 128 * 2);
    size_t need   = o_sup + (size_t)N * 256;   // bf16 support

    char* ws = (char*)d_ws;

    if (ws_size >= need && nbuck <= 512 && N <= (1 << 17) &&
        cap <= CAPMAX && chunkB <= REC_CAP) {
        int*      gcur = (int*)(ws + o_gcur);
        int*      rs   = (int*)(ws + o_rs);
        int*      re   = (int*)(ws + o_re);
        float*    dis  = (float*)(ws + o_dis);
        int*      csr  = (int*)(ws + o_csr);
        uint32_t* part = (uint32_t*)(ws + o_part);
        ushort*   wt   = (ushort*)(ws + o_wt);
        uint4*    sup  = (uint4*)(ws + o_sup);

        wconv_kernel<<<64, 256, 0, stream>>>(W, wt, gcur, nbuck);
        mfma_gemm<<<GB, 256, 0, stream>>>(x, wt, (uint32_t*)sup, N);
        build_kernel<<<NBLK_B, 256, 0, stream>>>(row, col, part, gcur,
                                                 E, chunkB, nbuck, cap);
        p3_build<<<nbuck, 1024, 0, stream>>>(part, gcur, rs, re, dis, csr,
                                             N, nbuck, cap);
        long long gthreads = (long long)N * 64;
        gather_kernel<<<(int)((gthreads + 255) / 256), 256, 0, stream>>>(
            csr, rs, re, dis, sup, bias, out, N);
    } else {
        // fallback: global-atomic CSR build + fp32 LDS GEMM + same gather
        size_t f_degi   = 0;
        size_t f_dis    = al(f_degi + (size_t)N * 4);
        size_t f_start  = al(f_dis + (size_t)N * 4);
        size_t f_rowptr = al(f_start + (size_t)N * 4);
        size_t f_bsum   = al(f_rowptr + ((size_t)N + 1) * 4);
        size_t f_csr    = al(f_bsum + 4096 * 4);
        size_t f_sup    = al(f_csr + (size_t)E * 4);

        int*      degi   = (int*)(ws + f_degi);
        float*    dis    = (float*)(ws + f_dis);
        int*      startv = (int*)(ws + f_start);
        int*      rowptr = (int*)(ws + f_rowptr);
        int*      bsum   = (int*)(ws + f_bsum);
        int*      csr    = (int*)(ws + f_csr);
        uint4*    sup    = (uint4*)(ws + f_sup);
        const int NBn = (N + SCAN_B - 1) / SCAN_B;

        hipMemsetAsync(degi, 0, (size_t)N * 4, stream);
        gemm_kernel<<<(N + GB_M - 1) / GB_M, 256, 0, stream>>>(x, W, (uint32_t*)sup, N);
        deg_i_kernel<<<(E + 255) / 256, 256, 0, stream>>>(row, degi, E);
        scan_block_kernel<<<NBn, SCAN_B, 0, stream>>>(degi, startv, bsum, N);
        scan_bsum_kernel<<<1, 1024, 0, stream>>>(bsum, NBn);
        scan_add_kernel<<<NBn, SCAN_B, 0, stream>>>(startv, bsum, N);
        rowptr_from_start_kernel<<<NBn, SCAN_B, 0, stream>>>(startv, rowptr, N, E);
        rsqrt_i_kernel<<<NBn, SCAN_B, 0, stream>>>(degi, dis, N);
        fill_kernel<<<(E + 255) / 256, 256, 0, stream>>>(row, col, startv, csr, E);
        long long gthreads = (long long)N * 64;
        gather_kernel<<<(int)((gthreads + 255) / 256), 256, 0, stream>>>(
            csr, rowptr, rowptr + 1, dis, sup, bias, out, N);
    }
}

// Round 13
// 132.779 us; speedup vs baseline: 1.0734x; 1.0734x over previous
//
#include <hip/hip_runtime.h>
#include <hip/hip_bf16.h>

// GCNConv: out = scatter_add_row( norm[e] * (x@W)[col[e]] ) + bias
// Round 13: restore R11 (best, 132.8us). Merged GEMM+build (overlap proven
// worth ~10us by R12 A/B), two-pass LDS counting-sort build, p3 @1024,
// wide gather at the 6.3 TB/s delivery roofline.

#define NBLK_B  512     // build blocks in merged kernel
#define BSHIFT  8       // 256 nodes per bucket
#define NPB     256
#define REC_CAP 3456    // max edges per build block chunk
#define CAPMAX  5632    // max records per bucket

typedef __attribute__((ext_vector_type(8))) short bf16x8;
typedef __attribute__((ext_vector_type(4))) float f32x4;

__device__ __forceinline__ uint32_t f2bf_rne(float f) {
    uint32_t u = __float_as_uint(f);
    return (u + 0x7fffu + ((u >> 16) & 1u)) >> 16;
}
__device__ __forceinline__ float bf_lo(uint32_t u) { return __uint_as_float(u << 16); }
__device__ __forceinline__ float bf_hi(uint32_t u) { return __uint_as_float(u & 0xffff0000u); }

__device__ __forceinline__ bf16x8 pack8(float4 lo, float4 hi) {
    union { bf16x8 v; ushort u[8]; } r;
    r.u[0] = (ushort)f2bf_rne(lo.x);
    r.u[1] = (ushort)f2bf_rne(lo.y);
    r.u[2] = (ushort)f2bf_rne(lo.z);
    r.u[3] = (ushort)f2bf_rne(lo.w);
    r.u[4] = (ushort)f2bf_rne(hi.x);
    r.u[5] = (ushort)f2bf_rne(hi.y);
    r.u[6] = (ushort)f2bf_rne(hi.z);
    r.u[7] = (ushort)f2bf_rne(hi.w);
    return r.v;
}

// ---------------- W -> Wt bf16 transposed; also zero bucket cursors ---------
__global__ void wconv_kernel(const float* __restrict__ W, ushort* __restrict__ Wt,
                             int* __restrict__ gcur, int nbuck) {
    int t = blockIdx.x * blockDim.x + threadIdx.x;   // 0..16383
    int n = t >> 7, k = t & 127;
    Wt[n * 128 + k] = (ushort)f2bf_rne(W[k * 128 + n]);
    if (t < nbuck) gcur[t] = 0;
}

// ---------------- merged: MFMA GEMM blocks + LDS-sorted partition blocks ----
__global__ __launch_bounds__(256) void merged_kernel(
        const float* __restrict__ X, const ushort* __restrict__ Wt,
        uint32_t* __restrict__ S, int N,
        const int* __restrict__ row, const int* __restrict__ col,
        uint32_t* __restrict__ part, int* __restrict__ gcur,
        int E, int chunk, int nbuck, int cap, int GB) {
    __shared__ __align__(16) char smem[26880];
    if ((int)blockIdx.x < GB) {
        // ---------- GEMM: S[N,128](bf16 pairs ch,ch+64) = X @ W ----------
        const int wave = threadIdx.x >> 6;
        const int lane = threadIdx.x & 63;
        const int c16  = lane & 15;
        const int kg   = lane >> 4;
        const int row0 = blockIdx.x * 128 + wave * 32;

        int rA0 = row0 + c16;
        int rA1 = row0 + 16 + c16;
        if (rA0 >= N) rA0 = N - 1;
        if (rA1 >= N) rA1 = N - 1;

        f32x4 acc[2][8];
#pragma unroll
        for (int m = 0; m < 2; ++m)
#pragma unroll
            for (int cb = 0; cb < 8; ++cb) acc[m][cb] = (f32x4){0.f, 0.f, 0.f, 0.f};

        const float*  xa0 = X + (size_t)rA0 * 128 + kg * 8;
        const float*  xa1 = X + (size_t)rA1 * 128 + kg * 8;
        const ushort* wb  = Wt + kg * 8 + c16 * 128;

#pragma unroll
        for (int kk = 0; kk < 4; ++kk) {
            float4 a0lo = *(const float4*)(xa0 + kk * 32);
            float4 a0hi = *(const float4*)(xa0 + kk * 32 + 4);
            float4 a1lo = *(const float4*)(xa1 + kk * 32);
            float4 a1hi = *(const float4*)(xa1 + kk * 32 + 4);
            bf16x8 A0 = pack8(a0lo, a0hi);
            bf16x8 A1 = pack8(a1lo, a1hi);
#pragma unroll
            for (int cb = 0; cb < 8; ++cb) {
                bf16x8 B = *(const bf16x8*)(wb + (size_t)cb * 16 * 128 + kk * 32);
                acc[0][cb] = __builtin_amdgcn_mfma_f32_16x16x32_bf16(A0, B, acc[0][cb], 0, 0, 0);
                acc[1][cb] = __builtin_amdgcn_mfma_f32_16x16x32_bf16(A1, B, acc[1][cb], 0, 0, 0);
            }
        }
#pragma unroll
        for (int m = 0; m < 2; ++m) {
#pragma unroll
            for (int i = 0; i < 4; ++i) {
                int gr = row0 + m * 16 + kg * 4 + i;
                if (gr < N) {
#pragma unroll
                    for (int cb = 0; cb < 4; ++cb) {
                        uint32_t p = f2bf_rne(acc[m][cb][i]) |
                                     (f2bf_rne(acc[m][cb + 4][i]) << 16);
                        S[(size_t)gr * 64 + cb * 16 + c16] = p;
                    }
                }
            }
        }
    } else {
        // ---------- build: LDS counting-sort, coalesced part write ----------
        uint32_t* rec  = (uint32_t*)smem;                 // [REC_CAP]
        ushort*   rbk  = (ushort*)(smem + 13824);         // [REC_CAP]
        int*      hist = (int*)(smem + 20736);            // [512]
        int*      lst  = (int*)(smem + 22784);            // [512]
        int*      resv = (int*)(smem + 24832);            // [512]
        const int blk = blockIdx.x - GB;
        const int t = threadIdx.x;
        int lo = blk * chunk, hi = min(E, lo + chunk);
        int cnt = hi - lo;

        for (int i = t; i < 512; i += 256) hist[i] = 0;
        __syncthreads();
        // pass 1: histogram by bucket
        for (int i = t; i < cnt; i += 256)
            atomicAdd(&hist[row[lo + i] >> BSHIFT], 1);
        __syncthreads();
        // exclusive scan of hist[0..511] (2 per thread; resv as scratch)
        int a0 = hist[2 * t], a1 = hist[2 * t + 1];
        int v2 = a0 + a1;
        resv[t] = v2;
        __syncthreads();
#pragma unroll
        for (int o = 1; o < 256; o <<= 1) {
            int u = (t >= o) ? resv[t - o] : 0;
            __syncthreads();
            resv[t] += u;
            __syncthreads();
        }
        int ex = resv[t] - v2;
        lst[2 * t]     = ex;
        lst[2 * t + 1] = ex + a0;
        __syncthreads();
        // reserve global ranges per bucket
        for (int b = t; b < nbuck; b += 256) {
            int c = hist[b];
            resv[b] = (c > 0) ? atomicAdd(&gcur[b], c) : 0;
        }
        __syncthreads();
        // cursors = local starts
        for (int i = t; i < 512; i += 256) hist[i] = lst[i];
        __syncthreads();
        // pass 2: re-read edges, scatter into LDS sorted order
        for (int i = t; i < cnt; i += 256) {
            int r = row[lo + i], c = col[lo + i];
            int b = r >> BSHIFT;
            int p = atomicAdd(&hist[b], 1);
            rec[p] = ((uint32_t)(r & (NPB - 1)) << 17) | (uint32_t)c;
            rbk[p] = (ushort)b;
        }
        __syncthreads();
        // coalesced write-out: per-bucket contiguous runs
        for (int i = t; i < cnt; i += 256) {
            int b = rbk[i];
            int off = resv[b] + (i - lst[b]);
            if (off < cap)
                part[(size_t)b * cap + off] = rec[i];
        }
    }
}

// ---------------- P3: per-bucket CSR via LDS image, coalesced out -----------
__global__ __launch_bounds__(1024) void p3_build(const uint32_t* __restrict__ part,
                                                 const int* __restrict__ gcur,
                                                 int* __restrict__ rowstart,
                                                 int* __restrict__ rowend,
                                                 float* __restrict__ dis,
                                                 int* __restrict__ csr,
                                                 int N, int nbuck, int cap) {
    __shared__ uint32_t recl[CAPMAX];
    __shared__ int csrl[CAPMAX];
    __shared__ int hist[NPB];
    __shared__ int lst[NPB];
    __shared__ int s[NPB];
    const int b = blockIdx.x, t = threadIdx.x;
    const int base = b * cap;
    int cb = gcur[b];
    if (cb > cap) cb = cap;

    if (t < NPB) hist[t] = 0;
    __syncthreads();
    for (int i = t; i < cb; i += 1024) {
        uint32_t p = part[base + i];
        recl[i] = p;
        atomicAdd(&hist[p >> 17], 1);
    }
    __syncthreads();

    int v = 0;
    if (t < NPB) { v = hist[t]; s[t] = v; }
    __syncthreads();
#pragma unroll
    for (int o = 1; o < NPB; o <<= 1) {
        int u = 0;
        if (t < NPB && t >= o) u = s[t - o];
        __syncthreads();
        if (t < NPB && t >= o) s[t] += u;
        __syncthreads();
    }
    if (t < NPB) {
        int ex = s[t] - v;
        lst[t] = ex;
        int node = (b << BSHIFT) + t;
        if (node < N) {
            rowstart[node] = base + ex;
            rowend[node]   = base + ex + v;
            dis[node]      = rsqrtf((float)v);
        }
        hist[t] = ex;    // cursor
    }
    __syncthreads();
    for (int i = t; i < cb; i += 1024) {
        uint32_t p = recl[i];
        int q = atomicAdd(&hist[p >> 17], 1);
        csrl[q] = (int)(p & 0x1FFFFu);
    }
    __syncthreads();
    for (int i = t; i < cb; i += 1024)
        csr[base + i] = csrl[i];
}

// ---------------- wide gather: 4 edges per VMEM instr (at roofline) ---------
__global__ __launch_bounds__(256) void gather_kernel(const int* __restrict__ csr,
                                                     const int* __restrict__ rowstart,
                                                     const int* __restrict__ rowend,
                                                     const float* __restrict__ dis,
                                                     const uint4* __restrict__ sup,
                                                     const float* __restrict__ bias,
                                                     float* __restrict__ out, int N) {
    int wid  = (blockIdx.x * blockDim.x + threadIdx.x) >> 6;
    int lane = threadIdx.x & 63;
    if (wid >= N) return;
    const int grp = lane >> 4;
    const int li  = lane & 15;
    int begin = rowstart[wid];
    int end   = rowend[wid];
    int endm1 = end - 1;
    float dr  = dis[wid];

    float4 aL = make_float4(0.f, 0.f, 0.f, 0.f);
    float4 aH = make_float4(0.f, 0.f, 0.f, 0.f);

    for (int j = begin; j < end; j += 8) {
        int e0 = j + grp, e1 = j + 4 + grp;
        int c0 = csr[min(e0, endm1)];
        int c1 = csr[min(e1, endm1)];
        float n0 = (e0 < end) ? dr * dis[c0] : 0.f;
        float n1 = (e1 < end) ? dr * dis[c1] : 0.f;
        uint4 u0 = sup[(size_t)c0 * 16 + li];
        uint4 u1 = sup[(size_t)c1 * 16 + li];
        aL.x += n0 * bf_lo(u0.x) + n1 * bf_lo(u1.x);
        aL.y += n0 * bf_lo(u0.y) + n1 * bf_lo(u1.y);
        aL.z += n0 * bf_lo(u0.z) + n1 * bf_lo(u1.z);
        aL.w += n0 * bf_lo(u0.w) + n1 * bf_lo(u1.w);
        aH.x += n0 * bf_hi(u0.x) + n1 * bf_hi(u1.x);
        aH.y += n0 * bf_hi(u0.y) + n1 * bf_hi(u1.y);
        aH.z += n0 * bf_hi(u0.z) + n1 * bf_hi(u1.z);
        aH.w += n0 * bf_hi(u0.w) + n1 * bf_hi(u1.w);
    }

#pragma unroll
    for (int off = 16; off < 64; off <<= 1) {
        aL.x += __shfl_xor(aL.x, off);
        aL.y += __shfl_xor(aL.y, off);
        aL.z += __shfl_xor(aL.z, off);
        aL.w += __shfl_xor(aL.w, off);
        aH.x += __shfl_xor(aH.x, off);
        aH.y += __shfl_xor(aH.y, off);
        aH.z += __shfl_xor(aH.z, off);
        aH.w += __shfl_xor(aH.w, off);
    }

    if (grp == 0) {
        float4 bL = *(const float4*)(bias + li * 4);
        float4 bH = *(const float4*)(bias + 64 + li * 4);
        aL.x += bL.x; aL.y += bL.y; aL.z += bL.z; aL.w += bL.w;
        aH.x += bH.x; aH.y += bH.y; aH.z += bH.z; aH.w += bH.w;
        *(float4*)(out + (size_t)wid * 128 + li * 4)      = aL;
        *(float4*)(out + (size_t)wid * 128 + 64 + li * 4) = aH;
    }
}

// ---------------- fallback path (global-atomic CSR build, fp32 GEMM) --------
#define SCAN_B 256
__global__ void scan_block_kernel(const int* __restrict__ in, int* __restrict__ outp,
                                  int* __restrict__ bsum, int M) {
    __shared__ int s[SCAN_B];
    int t = threadIdx.x;
    int g = blockIdx.x * SCAN_B + t;
    int v = (g < M) ? in[g] : 0;
    s[t] = v;
    __syncthreads();
#pragma unroll
    for (int off = 1; off < SCAN_B; off <<= 1) {
        int u = (t >= off) ? s[t - off] : 0;
        __syncthreads();
        s[t] += u;
        __syncthreads();
    }
    if (g < M) outp[g] = s[t] - v;
    if (t == SCAN_B - 1) bsum[blockIdx.x] = s[t];
}
__global__ void scan_bsum_kernel(int* __restrict__ bsum, int NB) {
    __shared__ int s[1024];
    int t = threadIdx.x;
    int v = (t < NB) ? bsum[t] : 0;
    s[t] = v;
    __syncthreads();
#pragma unroll
    for (int off = 1; off < 1024; off <<= 1) {
        int u = (t >= off) ? s[t - off] : 0;
        __syncthreads();
        s[t] += u;
        __syncthreads();
    }
    if (t < NB) bsum[t] = s[t] - v;
}
__global__ void scan_add_kernel(int* __restrict__ outp, const int* __restrict__ bsum, int M) {
    int g = blockIdx.x * blockDim.x + threadIdx.x;
    if (g < M) outp[g] += bsum[g >> 8];
}
#define GB_M 64
#define GB_KC 32
__global__ __launch_bounds__(256) void gemm_kernel(const float* __restrict__ X,
                                                   const float* __restrict__ W,
                                                   uint32_t* __restrict__ S, int N) {
    __shared__ float sXT[GB_KC][72];
    __shared__ float sW[GB_KC][128];
    const int t  = threadIdx.x;
    const int tx = t & 15;
    const int ty = t >> 4;
    const int bm = blockIdx.x * GB_M;

    float acc[4][8];
#pragma unroll
    for (int i = 0; i < 4; ++i)
#pragma unroll
        for (int j = 0; j < 8; ++j) acc[i][j] = 0.f;

    const int sr = t >> 2;
    const int sc = (t & 3) << 2;

    for (int k0 = 0; k0 < 128; k0 += GB_KC) {
#pragma unroll
        for (int h = 0; h < 2; ++h) {
            int kk = sc + h * 16;
            int gr = bm + sr;
            float4 v = make_float4(0.f, 0.f, 0.f, 0.f);
            if (gr < N) v = *(const float4*)(X + (size_t)gr * 128 + k0 + kk);
            sXT[kk + 0][sr] = v.x;
            sXT[kk + 1][sr] = v.y;
            sXT[kk + 2][sr] = v.z;
            sXT[kk + 3][sr] = v.w;
        }
#pragma unroll
        for (int h = 0; h < 4; ++h) {
            int idx = t + h * 256;
            int wk  = idx >> 5;
            int wo  = (idx & 31) << 2;
            *(float4*)&sW[wk][wo] = *(const float4*)(W + (size_t)(k0 + wk) * 128 + wo);
        }
        __syncthreads();
#pragma unroll
        for (int k = 0; k < GB_KC; ++k) {
            float4 a  = *(const float4*)&sXT[k][ty * 4];
            float4 b0 = *(const float4*)&sW[k][tx * 4];
            float4 b1 = *(const float4*)&sW[k][64 + tx * 4];
            float av[4] = {a.x, a.y, a.z, a.w};
            float bv[8] = {b0.x, b0.y, b0.z, b0.w, b1.x, b1.y, b1.z, b1.w};
#pragma unroll
            for (int i = 0; i < 4; ++i)
#pragma unroll
                for (int j = 0; j < 8; ++j) acc[i][j] += av[i] * bv[j];
        }
        __syncthreads();
    }
#pragma unroll
    for (int i = 0; i < 4; ++i) {
        int gr = bm + ty * 4 + i;
        if (gr < N) {
            uint4 q;
            q.x = f2bf_rne(acc[i][0]) | (f2bf_rne(acc[i][4]) << 16);
            q.y = f2bf_rne(acc[i][1]) | (f2bf_rne(acc[i][5]) << 16);
            q.z = f2bf_rne(acc[i][2]) | (f2bf_rne(acc[i][6]) << 16);
            q.w = f2bf_rne(acc[i][3]) | (f2bf_rne(acc[i][7]) << 16);
            *(uint4*)(S + (size_t)gr * 64 + tx * 4) = q;
        }
    }
}
__global__ void deg_i_kernel(const int* __restrict__ row, int* __restrict__ degi, int E) {
    int g = blockIdx.x * blockDim.x + threadIdx.x;
    if (g < E) atomicAdd(&degi[row[g]], 1);
}
__global__ void rsqrt_i_kernel(const int* __restrict__ degi, float* __restrict__ dis, int N) {
    int g = blockIdx.x * blockDim.x + threadIdx.x;
    if (g < N) dis[g] = rsqrtf((float)degi[g]);
}
__global__ void fill_kernel(const int* __restrict__ row, const int* __restrict__ col,
                            int* __restrict__ start, int* __restrict__ csr, int E) {
    int e = blockIdx.x * blockDim.x + threadIdx.x;
    if (e < E) {
        int pos = atomicAdd(&start[row[e]], 1);
        csr[pos] = col[e];
    }
}
__global__ void rowptr_from_start_kernel(const int* __restrict__ startv,
                                         int* __restrict__ rowptr, int N, int E) {
    int g = blockIdx.x * blockDim.x + threadIdx.x;
    if (g < N) rowptr[g] = startv[g];
    if (g == 0) rowptr[N] = E;
}

extern "C" void kernel_launch(void* const* d_in, const int* in_sizes, int n_in,
                              void* d_out, int out_size, void* d_ws, size_t ws_size,
                              hipStream_t stream) {
    const float* x    = (const float*)d_in[0];
    const int*   ei   = (const int*)d_in[1];
    const float* W    = (const float*)d_in[2];
    const float* bias = (const float*)d_in[3];
    float*       out  = (float*)d_out;

    const int N = in_sizes[0] / 128;
    const int E = in_sizes[1] / 2;
    const int* row = ei;
    const int* col = ei + E;

    const int nbuck = (N + NPB - 1) >> BSHIFT;
    int cap = (E + nbuck - 1) / nbuck;
    cap += cap / 4 + 128;
    cap = (cap + 63) & ~63;
    const int chunkB = (E + NBLK_B - 1) / NBLK_B;
    const int GB = (N + 127) / 128;

    auto al = [](size_t v) { return (v + 511) & ~(size_t)511; };
    size_t o_gcur = 0;
    size_t o_rs   = al(o_gcur + (size_t)nbuck * 4);
    size_t o_re   = al(o_rs + (size_t)N * 4);
    size_t o_dis  = al(o_re + (size_t)N * 4);
    size_t o_csr  = al(o_dis + (size_t)N * 4);
    size_t o_part = al(o_csr + (size_t)nbuck * cap * 4);
    size_t o_wt   = al(o_part + (size_t)nbuck * cap * 4);
    size_t o_sup  = al(o_wt + 128 * 128 * 2);
    size_t need   = o_sup + (size_t)N * 256;   // bf16 support

    char* ws = (char*)d_ws;

    if (ws_size >= need && nbuck <= 512 && N <= (1 << 17) &&
        cap <= CAPMAX && chunkB <= REC_CAP) {
        int*      gcur = (int*)(ws + o_gcur);
        int*      rs   = (int*)(ws + o_rs);
        int*      re   = (int*)(ws + o_re);
        float*    dis  = (float*)(ws + o_dis);
        int*      csr  = (int*)(ws + o_csr);
        uint32_t* part = (uint32_t*)(ws + o_part);
        ushort*   wt   = (ushort*)(ws + o_wt);
        uint4*    sup  = (uint4*)(ws + o_sup);

        wconv_kernel<<<64, 256, 0, stream>>>(W, wt, gcur, nbuck);
        merged_kernel<<<GB + NBLK_B, 256, 0, stream>>>(
            x, wt, (uint32_t*)sup, N, row, col, part, gcur,
            E, chunkB, nbuck, cap, GB);
        p3_build<<<nbuck, 1024, 0, stream>>>(part, gcur, rs, re, dis, csr,
                                             N, nbuck, cap);
        long long gthreads = (long long)N * 64;
        gather_kernel<<<(int)((gthreads + 255) / 256), 256, 0, stream>>>(
            csr, rs, re, dis, sup, bias, out, N);
    } else {
        // fallback: global-atomic CSR build + fp32 LDS GEMM + same gather
        size_t f_degi   = 0;
        size_t f_dis    = al(f_degi + (size_t)N * 4);
        size_t f_start  = al(f_dis + (size_t)N * 4);
        size_t f_rowptr = al(f_start + (size_t)N * 4);
        size_t f_bsum   = al(f_rowptr + ((size_t)N + 1) * 4);
        size_t f_csr    = al(f_bsum + 4096 * 4);
        size_t f_sup    = al(f_csr + (size_t)E * 4);

        int*      degi   = (int*)(ws + f_degi);
        float*    dis    = (float*)(ws + f_dis);
        int*      startv = (int*)(ws + f_start);
        int*      rowptr = (int*)(ws + f_rowptr);
        int*      bsum   = (int*)(ws + f_bsum);
        int*      csr    = (int*)(ws + f_csr);
        uint4*    sup    = (uint4*)(ws + f_sup);
        const int NBn = (N + SCAN_B - 1) / SCAN_B;

        hipMemsetAsync(degi, 0, (size_t)N * 4, stream);
        gemm_kernel<<<(N + GB_M - 1) / GB_M, 256, 0, stream>>>(x, W, (uint32_t*)sup, N);
        deg_i_kernel<<<(E + 255) / 256, 256, 0, stream>>>(row, degi, E);
        scan_block_kernel<<<NBn, SCAN_B, 0, stream>>>(degi, startv, bsum, N);
        scan_bsum_kernel<<<1, 1024, 0, stream>>>(bsum, NBn);
        scan_add_kernel<<<NBn, SCAN_B, 0, stream>>>(startv, bsum, N);
        rowptr_from_start_kernel<<<NBn, SCAN_B, 0, stream>>>(startv, rowptr, N, E);
        rsqrt_i_kernel<<<NBn, SCAN_B, 0, stream>>>(degi, dis, N);
        fill_kernel<<<(E + 255) / 256, 256, 0, stream>>>(row, col, startv, csr, E);
        long long gthreads = (long long)N * 64;
        gather_kernel<<<(int)((gthreads + 255) / 256), 256, 0, stream>>>(
            csr, rowptr, rowptr + 1, dis, sup, bias, out, N);
    }
}